// Round 9
// baseline (1674.350 us; speedup 1.0000x reference)
//
#include <hip/hip_runtime.h>
#include <hip/hip_bf16.h>
#include <stdint.h>

#define N_ATOMS 40000
#define N_BONDS 90000
#define MAX_NB 6
#define ATOM_FDIM 133
#define BOND_FDIM 147
#define HIDDEN 300
#define DEPTH 6

// padded dims
#define KB_PAD 160
#define KA_PAD 160
#define HP 320
#define NB_PAD 90112    // mult of 128 (704 tiles)
#define NA_PAD 40064

typedef unsigned short u16;
typedef unsigned int uint32;

typedef __bf16 bf16x8 __attribute__((ext_vector_type(8)));
typedef float f32x4 __attribute__((ext_vector_type(4)));

__device__ __forceinline__ float bf2f(u16 s) {
    union { uint32 u; float f; } v; v.u = ((uint32)s) << 16; return v.f;
}
__device__ __forceinline__ u16 f2bf(float f) {
    union { float f; uint32 u; } v; v.f = f;
    uint32 r = v.u + 0x7fffu + ((v.u >> 16) & 1u);
    return (u16)(r >> 16);
}
__device__ __forceinline__ uint32 cvt_pk_bf16(float lo, float hi) {
    uint32 r;
    asm("v_cvt_pk_bf16_f32 %0, %1, %2" : "=v"(r) : "v"(lo), "v"(hi));
    return r;
}
__device__ __forceinline__ u16 f2bf1(float f) {
    return (u16)(cvt_pk_bf16(f, f) & 0xffffu);
}
__device__ __forceinline__ float sigm(float x) { return 1.f / (1.f + __expf(-x)); }
__device__ __forceinline__ float tanh_s(float x) {
    float e = __expf(-2.f * fabsf(x));
    float t = (1.f - e) / (1.f + e);
    return x >= 0.f ? t : -t;
}

// ---------------------------------------------------------------------------
// Register-streaming GEMM: NO LDS, NO barriers, NO manual waitcnt.
// R8 ablation: every barrier-lockstep k-loop variant (4-buf counted-vmcnt,
// 2-buf, fully-serial, 1.5x occupancy, no-setprio) lands within +-4% -- the
// cost is a fixed per-kstep toll of the lockstep structure itself. So this
// round removes the structure: both MFMA operands are loaded fragment-direct
// global->VGPR (the 16x16x32 A- AND B-fragment layouts are plain row-major
// 16 B/lane reads; A verified in R7, B is the same pattern on B rows).
// All operands are L2-resident (B = 1.2 MB; A panels L2-local via XCD swizzle).
// Per wave per kstep: 4 A-loads + 2*NG B-loads (saddr form: uniform base +
// 32-bit lane offset, ks*64 folds into the 13-bit inst offset) + NG*8 MFMA.
// Distance-1 register double-buffer aF/bF[2] (R6-verified parity: loadK(j+1)
// writes set (j+1)&1 while compute(j) reads j&1); full unroll; the compiler
// inserts counted vmcnt per fragment use. Waves fully decoupled: ILP +
// 2 waves/SIMD hide L2 latency. Tradeoff accepted: 2x operand re-read across
// the 2M x 2N wave grid (~600 KB/block from L2 ~= 61 us L2 floor).
//
// EPI 3 gate sparsity: slot2 = i_n rows (ks<KSPLIT) / h_n rows (ks>=KSPLIT).
// EPI 0: store bf16. EPI 2: bias+relu+mask fp32 out. EPI 3: fused GRU.
// ---------------------------------------------------------------------------
template<int NG, int EPI, int SWZ, int KSTEPS, int KSPLIT>
__global__ __launch_bounds__(256, 2) void gemm_k(
    const u16* __restrict__ A, int ldaB,
    const u16* __restrict__ A2, int lda2B,
    const u16* __restrict__ Bw, int ldbB,
    int M,
    u16* __restrict__ C1, int ldc,
    const float* __restrict__ bias,
    const u16* __restrict__ hbuf,
    float* __restrict__ outp, const float* __restrict__ omask)
{
    constexpr int NACC = (EPI == 3) ? 4 : NG;

    const int tid = threadIdx.x;
    const int wv = tid >> 6, ln = tid & 63;
    const int wm = wv >> 1, wn = wv & 1;        // 2M x 2N wave grid
    int bxi, byi;
    if constexpr (SWZ) {
        int bid = blockIdx.x;
        int chunk = bid & 7, pos = bid >> 3;
        int orig = chunk * (int)(gridDim.x >> 3) + pos;
        bxi = orig / 5; byi = orig - bxi * 5;
    } else {
        bxi = blockIdx.x; byi = blockIdx.y;
    }
    const int m0 = bxi * 128;
    const int n0 = byi * 64;
    const int lhalf = ln >> 4, l16 = ln & 15;

    f32x4 acc[NACC][4][2];
#pragma unroll
    for (int g = 0; g < NACC; ++g)
#pragma unroll
        for (int r = 0; r < 4; ++r)
#pragma unroll
            for (int c = 0; c < 2; ++c) { f32x4 z = {0.f, 0.f, 0.f, 0.f}; acc[g][r][c] = z; }

    // ---- 32-bit lane byte-offsets (saddr-form loads: uniform base + voffset) ----
    int offA[4], offA2[4];
#pragma unroll
    for (int r = 0; r < 4; ++r) {
        int row = m0 + wm * 64 + r * 16 + l16;
        offA[r]  = row * ldaB  + lhalf * 16;
        offA2[r] = row * lda2B + lhalf * 16;
    }
    int offB[NG][2];
#pragma unroll
    for (int g = 0; g < NG; ++g)
#pragma unroll
        for (int c = 0; c < 2; ++c)
            offB[g][c] = (g * 320 + n0 + wn * 32 + c * 16 + l16) * ldbB + lhalf * 16;
    int offB2hi[2];
#pragma unroll
    for (int c = 0; c < 2; ++c)
        offB2hi[c] = (3 * 320 + n0 + wn * 32 + c * 16 + l16) * ldbB + lhalf * 16;

    bf16x8 aF[2][4];
    bf16x8 bF[2][NG][2];

    auto loadK = [&](int ks) {
        const int s = ks & 1;
#pragma unroll
        for (int r = 0; r < 4; ++r) {
            const char* src = (ks < KSPLIT)
                ? (const char*)A  + offA[r]  + ks * 64
                : (const char*)A2 + offA2[r] + (ks - KSPLIT) * 64;
            aF[s][r] = *(const bf16x8*)src;
        }
#pragma unroll
        for (int g = 0; g < NG; ++g)
#pragma unroll
            for (int c = 0; c < 2; ++c) {
                int off;
                if constexpr (EPI == 3) {
                    off = (g == 2 && ks >= KSPLIT) ? offB2hi[c] : offB[g][c];
                } else {
                    off = offB[g][c];
                }
                bF[s][g][c] = *(const bf16x8*)((const char*)Bw + off + ks * 64);
            }
    };

    auto compute = [&](int j) {
        const int s = j & 1;
#pragma unroll
        for (int g = 0; g < NG; ++g) {
#pragma unroll
            for (int c = 0; c < 2; ++c) {
#pragma unroll
                for (int r = 0; r < 4; ++r) {
                    if constexpr (EPI == 3) {
                        if (g == 2) {
                            if (j < KSPLIT)
                                acc[2][r][c] = __builtin_amdgcn_mfma_f32_16x16x32_bf16(aF[s][r], bF[s][g][c], acc[2][r][c], 0, 0, 0);
                            else
                                acc[3][r][c] = __builtin_amdgcn_mfma_f32_16x16x32_bf16(aF[s][r], bF[s][g][c], acc[3][r][c], 0, 0, 0);
                        } else {
                            acc[g][r][c] = __builtin_amdgcn_mfma_f32_16x16x32_bf16(aF[s][r], bF[s][g][c], acc[g][r][c], 0, 0, 0);
                        }
                    } else {
                        acc[g][r][c] = __builtin_amdgcn_mfma_f32_16x16x32_bf16(aF[s][r], bF[s][g][c], acc[g][r][c], 0, 0, 0);
                    }
                }
            }
        }
    };

    loadK(0);
#pragma unroll
    for (int j = 0; j < KSTEPS; ++j) {
        if (j + 1 < KSTEPS) loadK(j + 1);   // writes set (j+1)&1; compute reads j&1
        compute(j);
    }

    const int mrow_base = m0 + wm * 64;
#pragma unroll
    for (int r = 0; r < 4; ++r) {
#pragma unroll
        for (int c = 0; c < 2; ++c) {
            int nn_ = n0 + wn * 32 + c * 16 + l16;
#pragma unroll
            for (int i = 0; i < 4; ++i) {
                int m = mrow_base + r * 16 + lhalf * 4 + i;
                if (m >= M) continue;
                if constexpr (EPI == 0) {
#pragma unroll
                    for (int g = 0; g < NG; ++g) {
                        float v = acc[g][r][c][i];
                        if (bias != nullptr && nn_ < HIDDEN) v += bias[g * HIDDEN + nn_];
                        C1[(size_t)m * ldc + g * 320 + nn_] = f2bf1(v);
                    }
                } else if constexpr (EPI == 2) {
                    if (nn_ < HIDDEN) {
                        float v = acc[0][r][c][i] + (bias ? bias[nn_] : 0.f);
                        v = fmaxf(v, 0.f);
                        if (omask) v *= omask[m];
                        outp[(size_t)m * HIDDEN + nn_] = v;
                    }
                } else { // EPI == 3: fused GRU
                    float rl = acc[0][r][c][i] + bias[nn_];
                    float zl = acc[1][r][c][i] + bias[320 + nn_];
                    float in_ = acc[2][r][c][i] + bias[640 + nn_];
                    float hn_ = acc[3][r][c][i] + bias[960 + nn_];
                    float hv = bf2f(hbuf[(size_t)m * HP + nn_]);
                    float rr = sigm(rl);
                    float zz = sigm(zl);
                    float nv = tanh_s(in_ + rr * hn_);
                    float msg = (1.f - zz) * nv + zz * hv;
                    if (m == 0) msg = 0.f;
                    C1[(size_t)m * HP + nn_] = f2bf1(msg);
                }
            }
        }
    }
}

// a_message[a, :] = sum_j message[a2b[a,j], :]
__global__ __launch_bounds__(256) void gather_sum_k(
    const u16* __restrict__ msg, const int* __restrict__ a2b, u16* __restrict__ amsg)
{
    int u = blockIdx.x * 256 + threadIdx.x;
    if (u >= N_ATOMS * 40) return;
    int a = u / 40, c = u - a * 40;
    const uint4* mp = (const uint4*)msg;
    float s[8];
#pragma unroll
    for (int t = 0; t < 8; ++t) s[t] = 0.f;
#pragma unroll
    for (int j = 0; j < MAX_NB; ++j) {
        int b = a2b[a * MAX_NB + j];
        uint4 v = mp[(size_t)b * 40 + c];
        s[0] += bf2f((u16)(v.x & 0xffff)); s[1] += bf2f((u16)(v.x >> 16));
        s[2] += bf2f((u16)(v.y & 0xffff)); s[3] += bf2f((u16)(v.y >> 16));
        s[4] += bf2f((u16)(v.z & 0xffff)); s[5] += bf2f((u16)(v.z >> 16));
        s[6] += bf2f((u16)(v.w & 0xffff)); s[7] += bf2f((u16)(v.w >> 16));
    }
    uint4 o;
    o.x = cvt_pk_bf16(s[0], s[1]);
    o.y = cvt_pk_bf16(s[2], s[3]);
    o.z = cvt_pk_bf16(s[4], s[5]);
    o.w = cvt_pk_bf16(s[6], s[7]);
    ((uint4*)amsg)[(size_t)a * 40 + c] = o;
}

// h[b, :] = amsg[b2a[b], :] - msg[b2revb[b], :]
__global__ __launch_bounds__(256) void build_h_k(
    const u16* __restrict__ amsg, const u16* __restrict__ msg,
    const int* __restrict__ b2a, const int* __restrict__ b2revb, u16* __restrict__ h)
{
    int u = blockIdx.x * 256 + threadIdx.x;
    if (u >= N_BONDS * 40) return;
    int b = u / 40, c = u - b * 40;
    uint4 va = ((const uint4*)amsg)[(size_t)b2a[b] * 40 + c];
    uint4 vm = ((const uint4*)msg)[(size_t)b2revb[b] * 40 + c];
    uint4 o;
    o.x = cvt_pk_bf16(bf2f((u16)(va.x & 0xffff)) - bf2f((u16)(vm.x & 0xffff)),
                      bf2f((u16)(va.x >> 16))    - bf2f((u16)(vm.x >> 16)));
    o.y = cvt_pk_bf16(bf2f((u16)(va.y & 0xffff)) - bf2f((u16)(vm.y & 0xffff)),
                      bf2f((u16)(va.y >> 16))    - bf2f((u16)(vm.y >> 16)));
    o.z = cvt_pk_bf16(bf2f((u16)(va.z & 0xffff)) - bf2f((u16)(vm.z & 0xffff)),
                      bf2f((u16)(va.z >> 16))    - bf2f((u16)(vm.z >> 16)));
    o.w = cvt_pk_bf16(bf2f((u16)(va.w & 0xffff)) - bf2f((u16)(vm.w & 0xffff)),
                      bf2f((u16)(va.w >> 16))    - bf2f((u16)(vm.w >> 16)));
    ((uint4*)h)[(size_t)b * 40 + c] = o;
}

// generic pad+cast fp32 -> bf16
__global__ __launch_bounds__(256) void padcast_k(
    const float* __restrict__ src, int srows, int scols,
    u16* __restrict__ dst, int drows, int dcols)
{
    int idx = blockIdx.x * 256 + threadIdx.x;
    if (idx >= drows * dcols) return;
    int r = idx / dcols, c = idx - r * dcols;
    float v = (r < srows && c < scols) ? src[(size_t)r * scols + c] : 0.f;
    dst[idx] = f2bf(v);
}

// Wf[900][160] fp32 = W_ih[900][300] @ W_i[300][147]
__global__ __launch_bounds__(256) void wf_k(
    const float* __restrict__ W_ih, const float* __restrict__ W_i, float* __restrict__ Wf)
{
    int idx = blockIdx.x * 256 + threadIdx.x;
    if (idx >= 900 * 160) return;
    int r = idx / 160, c = idx - r * 160;
    float s = 0.f;
    if (c < BOND_FDIM) {
        for (int k = 0; k < HIDDEN; ++k)
            s += W_ih[(size_t)r * HIDDEN + k] * W_i[(size_t)k * BOND_FDIM + c];
    }
    Wf[idx] = s;
}

// W4[4][320][480]
__global__ __launch_bounds__(256) void prep_W4_k(
    const float* __restrict__ Wf, const float* __restrict__ W_hh, u16* __restrict__ W4)
{
    int idx = blockIdx.x * 256 + threadIdx.x;
    if (idx >= 4 * HP * 480) return;
    int g = idx / (HP * 480); int rem = idx - g * HP * 480;
    int n = rem / 480, k = rem - n * 480;
    float v = 0.f;
    if (n < HIDDEN) {
        if (g <= 1) {
            if (k < KB_PAD) v = Wf[(size_t)(g * HIDDEN + n) * 160 + k];
            else if (k < KB_PAD + HIDDEN) v = W_hh[(size_t)(g * HIDDEN + n) * HIDDEN + (k - KB_PAD)];
        } else if (g == 2) {
            if (k < KB_PAD) v = Wf[(size_t)(2 * HIDDEN + n) * 160 + k];
        } else {
            if (k >= KB_PAD && k < KB_PAD + HIDDEN) v = W_hh[(size_t)(2 * HIDDEN + n) * HIDDEN + (k - KB_PAD)];
        }
    }
    W4[idx] = f2bf(v);
}

// bias4[4*320]
__global__ __launch_bounds__(256) void bias4_k(
    const float* __restrict__ b_ih, const float* __restrict__ b_hh, float* __restrict__ b4)
{
    int idx = blockIdx.x * 256 + threadIdx.x;
    if (idx >= 4 * HP) return;
    int g = idx / HP, n = idx - g * HP;
    float v = 0.f;
    if (n < HIDDEN) {
        if (g == 0) v = b_ih[n] + b_hh[n];
        else if (g == 1) v = b_ih[HIDDEN + n] + b_hh[HIDDEN + n];
        else if (g == 2) v = b_ih[2 * HIDDEN + n];
        else v = b_hh[2 * HIDDEN + n];
    }
    b4[idx] = v;
}

// W_o [300][433] -> [320][480]
__global__ __launch_bounds__(256) void padWo_k(const float* __restrict__ src, u16* __restrict__ dst)
{
    int idx = blockIdx.x * 256 + threadIdx.x;
    if (idx >= HP * 480) return;
    int n = idx / 480, k = idx - n * 480;
    float v = 0.f;
    if (n < HIDDEN) {
        if (k < ATOM_FDIM) v = src[(size_t)n * 433 + k];
        else if (k >= KA_PAD && k < KA_PAD + HIDDEN) v = src[(size_t)n * 433 + ATOM_FDIM + (k - KA_PAD)];
    }
    dst[idx] = f2bf(v);
}

__global__ __launch_bounds__(256) void sentinel_k(float* __restrict__ out, int n)
{
    int i = blockIdx.x * 256 + threadIdx.x;
    if (i < n) out[i] = 31415.0f;
}

extern "C" void kernel_launch(void* const* d_in, const int* in_sizes, int n_in,
                              void* d_out, int out_size, void* d_ws, size_t ws_size,
                              hipStream_t stream)
{
    const float* f_atoms = (const float*)d_in[0];
    const float* f_bonds = (const float*)d_in[1];
    const int*   a2b     = (const int*)d_in[2];
    const int*   b2a     = (const int*)d_in[3];
    const int*   b2revb  = (const int*)d_in[4];
    const float* maskp   = (const float*)d_in[8];
    const float* W_i     = (const float*)d_in[9];
    const float* W_ih    = (const float*)d_in[10];
    const float* W_hh    = (const float*)d_in[11];
    const float* b_ih    = (const float*)d_in[12];
    const float* b_hh    = (const float*)d_in[13];
    const float* W_o_w   = (const float*)d_in[14];
    const float* W_o_b   = (const float*)d_in[15];
    float* out = (float*)d_out;

    char* ws = (char*)d_ws;
    size_t off = 0;
    auto alloc = [&](size_t bytes) -> char* {
        char* p = ws + off;
        off += (bytes + 255) & ~(size_t)255;
        return p;
    };
    u16*   Wi_p   = (u16*)alloc((size_t)HP * KB_PAD * 2);
    u16*   W4     = (u16*)alloc((size_t)4 * HP * 480 * 2);
    u16*   Wo_p   = (u16*)alloc((size_t)HP * 480 * 2);
    float* bias4  = (float*)alloc((size_t)4 * HP * 4);
    float* Wf     = (float*)alloc((size_t)900 * 160 * 4);
    u16*   fa_p   = (u16*)alloc((size_t)NA_PAD * KA_PAD * 2);
    u16*   fb_p   = (u16*)alloc((size_t)NB_PAD * KB_PAD * 2);
    u16*   message= (u16*)alloc((size_t)NB_PAD * HP * 2);
    u16*   hbuf   = (u16*)alloc((size_t)NB_PAD * HP * 2);
    u16*   amsg   = (u16*)alloc((size_t)NA_PAD * HP * 2);

    if (off > ws_size) {
        sentinel_k<<<(out_size + 255) / 256, 256, 0, stream>>>(out, out_size);
        return;
    }

    // --- weight / feature prep ---
    padcast_k<<<(HP * KB_PAD + 255) / 256, 256, 0, stream>>>(W_i, HIDDEN, BOND_FDIM, Wi_p, HP, KB_PAD);
    padcast_k<<<(NB_PAD * KB_PAD + 255) / 256, 256, 0, stream>>>(f_bonds, N_BONDS, BOND_FDIM, fb_p, NB_PAD, KB_PAD);
    padcast_k<<<(NA_PAD * KA_PAD + 255) / 256, 256, 0, stream>>>(f_atoms, N_ATOMS, ATOM_FDIM, fa_p, NA_PAD, KA_PAD);
    wf_k<<<(900 * 160 + 255) / 256, 256, 0, stream>>>(W_ih, W_i, Wf);
    prep_W4_k<<<(4 * HP * 480 + 255) / 256, 256, 0, stream>>>(Wf, W_hh, W4);
    bias4_k<<<(4 * HP + 255) / 256, 256, 0, stream>>>(b_ih, b_hh, bias4);
    padWo_k<<<(HP * 480 + 255) / 256, 256, 0, stream>>>(W_o_w, Wo_p);

    dim3 blk(256);
    dim3 gB(NB_PAD / 128, 5);
    // message = inp = f_bonds @ W_i.T   (K=160 -> 5 ksteps, A only)
    gemm_k<1, 0, 0, 5, 5><<<gB, blk, 0, stream>>>(
        fb_p, KB_PAD * 2, fb_p, KB_PAD * 2, Wi_p, KB_PAD * 2,
        N_BONDS, message, HP, nullptr, nullptr, nullptr, nullptr);

    dim3 gBf(NB_PAD / 128 * 5);      // 3520, %8==0 -> bijective XCD swizzle
    for (int d = 0; d < DEPTH - 1; ++d) {
        gather_sum_k<<<(N_ATOMS * 40 + 255) / 256, 256, 0, stream>>>(message, a2b, amsg);
        build_h_k<<<(N_BONDS * 40 + 255) / 256, 256, 0, stream>>>(amsg, message, b2a, b2revb, hbuf);
        // fused GRU: A = [f_bonds_pad | h], 3 B-slots, 4 acc gates, K = 480
        gemm_k<3, 3, 1, 15, 5><<<gBf, blk, 0, stream>>>(
            fb_p, KB_PAD * 2, hbuf, HP * 2, W4, 480 * 2,
            N_BONDS, message, HP, bias4, hbuf, nullptr, nullptr);
    }
    gather_sum_k<<<(N_ATOMS * 40 + 255) / 256, 256, 0, stream>>>(message, a2b, amsg);
    dim3 gO(NA_PAD / 128, 5);
    gemm_k<1, 2, 0, 15, 5><<<gO, blk, 0, stream>>>(
        fa_p, KA_PAD * 2, amsg, HP * 2, Wo_p, 480 * 2,
        N_ATOMS, nullptr, 0, W_o_b, nullptr, out, maskp);
}

// Round 10
// 1350.534 us; speedup vs baseline: 1.2398x; 1.2398x over previous
//
#include <hip/hip_runtime.h>
#include <hip/hip_bf16.h>
#include <stdint.h>

#define N_ATOMS 40000
#define N_BONDS 90000
#define MAX_NB 6
#define ATOM_FDIM 133
#define BOND_FDIM 147
#define HIDDEN 300
#define DEPTH 6

// padded dims
#define KB_PAD 160
#define KA_PAD 160
#define HP 320
#define NB_PAD 90112    // mult of 128 (704 tiles)
#define NA_PAD 40064

typedef unsigned short u16;
typedef unsigned int uint32;

typedef __bf16 bf16x8 __attribute__((ext_vector_type(8)));
typedef float f32x4 __attribute__((ext_vector_type(4)));

#define GLOBAL_AS __attribute__((address_space(1)))
#define LDS_AS __attribute__((address_space(3)))

__device__ __forceinline__ void async_copy16(const void* g, void* l) {
    __builtin_amdgcn_global_load_lds((GLOBAL_AS void*)(void*)g,
                                     (LDS_AS void*)l, 16, 0, 0);
}

__device__ __forceinline__ float bf2f(u16 s) {
    union { uint32 u; float f; } v; v.u = ((uint32)s) << 16; return v.f;
}
__device__ __forceinline__ u16 f2bf(float f) {
    union { float f; uint32 u; } v; v.f = f;
    uint32 r = v.u + 0x7fffu + ((v.u >> 16) & 1u);
    return (u16)(r >> 16);
}
__device__ __forceinline__ uint32 cvt_pk_bf16(float lo, float hi) {
    uint32 r;
    asm("v_cvt_pk_bf16_f32 %0, %1, %2" : "=v"(r) : "v"(lo), "v"(hi));
    return r;
}
__device__ __forceinline__ u16 f2bf1(float f) {
    return (u16)(cvt_pk_bf16(f, f) & 0xffffu);
}
__device__ __forceinline__ float sigm(float x) { return 1.f / (1.f + __expf(-x)); }
__device__ __forceinline__ float tanh_s(float x) {
    float e = __expf(-2.f * fabsf(x));
    float t = (1.f - e) / (1.f + e);
    return x >= 0.f ? t : -t;
}

#define WAITV(n) asm volatile("s_waitcnt vmcnt(" #n ")" ::: "memory")
#define MEMFENCE asm volatile("" ::: "memory")

// ---------------------------------------------------------------------------
// GEMM, R10: R8-V0 verified skeleton (4-buf counted-vmcnt, T2 swizzle,
// conflicts==0, gate sparsity) + PHASE-ALIGNMENT FIX in compute().
//
// Diagnosis (R8 ablation + R9 + m06 per-CU MFMA ceiling): per kstep-round a
// CU needs ~930 cyc of matrix pipe (192 MFMA x 4.85, CU-wide pipe) and ~960
// cyc of LDS pipe (80 ds_read_b128 x 12). Every barrier-lockstep variant ran
// ~2050 cyc/round: the per-kstep barrier phase-aligns all 8 waves, so all
// ds_read clusters run together (matrix idle) then all MFMA clusters (LDS
// idle) -- the pipes SERIALIZE. Fix: interleave ds_read/MFMA inside each
// kstep, pinned by sched_group_barrier:
//   (DS_READ 6: A x4 + B_g0 x2)(MFMA 8)(DS 2: B_g1)(MFMA 8)(DS 2: B_g2)(MFMA 8)
// so both pipes are exercised throughout the kstep and cross-wave overlap
// is possible. setprio kept (phase-split = T5's prerequisite, now present).
//
// EPI 3 gate sparsity: slot2 = i_n (ks<KSPLIT) / h_n (else).
// EPI 0: store bf16. EPI 2: bias+relu+mask fp32 out. EPI 3: fused GRU.
// ---------------------------------------------------------------------------
template<int NG, int EPI, int SWZ, int KSTEPS, int KSPLIT>
__global__ __launch_bounds__(256, 2) void gemm_k(
    const u16* __restrict__ A, int ldaB,
    const u16* __restrict__ A2, int lda2B,
    const u16* __restrict__ Bw, int ldbB,
    int M,
    u16* __restrict__ C1, int ldc,
    const float* __restrict__ bias,
    const u16* __restrict__ hbuf,
    float* __restrict__ outp, const float* __restrict__ omask)
{
    constexpr int NACC = (EPI == 3) ? 4 : NG;
    __shared__ __align__(16) u16 lsA[4][128 * 32];
    __shared__ __align__(16) u16 lsB[4][NG * 64 * 32];

    const int tid = threadIdx.x;
    const int wv = tid >> 6, ln = tid & 63;
    const int wm = wv >> 1, wn = wv & 1;        // 2M x 2N wave grid
    int bxi, byi;
    if constexpr (SWZ) {
        int bid = blockIdx.x;
        int chunk = bid & 7, pos = bid >> 3;
        int orig = chunk * (int)(gridDim.x >> 3) + pos;
        bxi = orig / 5; byi = orig - bxi * 5;
    } else {
        bxi = blockIdx.x; byi = blockIdx.y;
    }
    const int m0 = bxi * 128;
    const int n0 = byi * 64;
    const int lhalf = ln >> 4, l16 = ln & 15;

    f32x4 acc[NACC][4][2];
#pragma unroll
    for (int g = 0; g < NACC; ++g)
#pragma unroll
        for (int r = 0; r < 4; ++r)
#pragma unroll
            for (int c = 0; c < 2; ++c) { f32x4 z = {0.f, 0.f, 0.f, 0.f}; acc[g][r][c] = z; }

    // ---- staging bases (source pre-swizzled; glds dest lane-linear) ----
    const char* pA[2];
    const char* pA2[2];
#pragma unroll
    for (int c = 0; c < 2; ++c) {
        int idx = (wv * 2 + c) * 64 + ln;       // 16B-unit index
        int row = idx >> 2;
        int kb = ((idx & 3) * 16) ^ (((row >> 1) & 3) << 4);
        pA[c]  = (const char*)A  + (size_t)(m0 + row) * ldaB  + kb;
        pA2[c] = (const char*)A2 + (size_t)(m0 + row) * lda2B + kb;
    }
    const int bidx = wv * 64 + ln;
    const int bn = bidx >> 2;
    const int bkb = ((bidx & 3) * 16) ^ (((bn >> 1) & 3) << 4);
    const char* pB[NG];
#pragma unroll
    for (int g = 0; g < NG; ++g)
        pB[g] = (const char*)Bw + (size_t)(g * 320 + n0 + bn) * ldbB + bkb;
    const char* pB2hi = (const char*)Bw + (size_t)(3 * 320 + n0 + bn) * ldbB + bkb;

    auto stage = [&](int ks, int buf) {
#pragma unroll
        for (int c = 0; c < 2; ++c) {
            const char* src = (ks < KSPLIT) ? (pA[c] + ks * 64)
                                            : (pA2[c] + (ks - KSPLIT) * 64);
            async_copy16(src, &lsA[buf][(wv * 2 + c) * 512]);
        }
#pragma unroll
        for (int g = 0; g < NG; ++g) {
            const char* src;
            if constexpr (EPI == 3) {
                if (g == 2) src = ((ks < KSPLIT) ? pB[2] : pB2hi) + ks * 64;
                else        src = pB[g] + ks * 64;
            } else {
                src = pB[g] + ks * 64;
            }
            async_copy16(src, &lsB[buf][g * 2048 + wv * 512]);
        }
    };

    const int rswz = ((l16 >> 1) & 3) << 3;      // read-side swizzle (u16 units)

    // Interleaved compute: ds_read and MFMA alternate inside each kstep so the
    // CU's LDS pipe and matrix pipe overlap across the 8 barrier-aligned waves.
    auto compute = [&](int j, int buf) {
        __builtin_amdgcn_s_setprio(1);
        bf16x8 af[4];
#pragma unroll
        for (int r = 0; r < 4; ++r)
            af[r] = *(const bf16x8*)&lsA[buf][(wm * 64 + r * 16 + l16) * 32 + (lhalf * 8 ^ rswz)];
        if constexpr (EPI == 3) {
#define GATE(gc) do {                                                            \
            constexpr int g_ = (gc);                                            \
            _Pragma("unroll")                                                    \
            for (int c = 0; c < 2; ++c) {                                        \
                bf16x8 bf = *(const bf16x8*)&lsB[buf][g_ * 2048 +                \
                    (wn * 32 + c * 16 + l16) * 32 + (lhalf * 8 ^ rswz)];         \
                _Pragma("unroll")                                                \
                for (int r = 0; r < 4; ++r) {                                    \
                    if constexpr (g_ == 2) {                                     \
                        if (j < KSPLIT)                                          \
                            acc[2][r][c] = __builtin_amdgcn_mfma_f32_16x16x32_bf16(af[r], bf, acc[2][r][c], 0, 0, 0); \
                        else                                                     \
                            acc[3][r][c] = __builtin_amdgcn_mfma_f32_16x16x32_bf16(af[r], bf, acc[3][r][c], 0, 0, 0); \
                    } else {                                                     \
                        acc[g_][r][c] = __builtin_amdgcn_mfma_f32_16x16x32_bf16(af[r], bf, acc[g_][r][c], 0, 0, 0);   \
                    }                                                            \
                }                                                                \
            } } while (0)
            GATE(0);
            GATE(1);
            GATE(2);
#undef GATE
            // T19 pinning: alternate DS_READ (0x100) and MFMA (0x8) groups
            __builtin_amdgcn_sched_group_barrier(0x100, 6, 0); // A x4 + B_g0 x2
            __builtin_amdgcn_sched_group_barrier(0x008, 8, 0); // MFMA g0
            __builtin_amdgcn_sched_group_barrier(0x100, 2, 0); // B_g1
            __builtin_amdgcn_sched_group_barrier(0x008, 8, 0); // MFMA g1
            __builtin_amdgcn_sched_group_barrier(0x100, 2, 0); // B_g2
            __builtin_amdgcn_sched_group_barrier(0x008, 8, 0); // MFMA g2
        } else {
#pragma unroll
            for (int c = 0; c < 2; ++c) {
                bf16x8 bf = *(const bf16x8*)&lsB[buf][(wn * 32 + c * 16 + l16) * 32 + (lhalf * 8 ^ rswz)];
#pragma unroll
                for (int r = 0; r < 4; ++r)
                    acc[0][r][c] = __builtin_amdgcn_mfma_f32_16x16x32_bf16(af[r], bf, acc[0][r][c], 0, 0, 0);
            }
            __builtin_amdgcn_sched_group_barrier(0x100, 5, 0); // A x4 + B_c0
            __builtin_amdgcn_sched_group_barrier(0x008, 4, 0); // MFMA c0
            __builtin_amdgcn_sched_group_barrier(0x100, 1, 0); // B_c1
            __builtin_amdgcn_sched_group_barrier(0x008, 4, 0); // MFMA c1
        }
        __builtin_amdgcn_s_setprio(0);
    };

    // prologue: fill 3 of 4 buffers (counted-vmcnt protocol, R4/R8-verified)
    stage(0, 0); MEMFENCE; stage(1, 1); MEMFENCE; stage(2, 2);

#pragma unroll
    for (int j = 0; j < KSTEPS; ++j) {
        const int rem = KSTEPS - 1 - j;
        const int d = rem > 2 ? 2 : rem;         // stages legitimately in flight
        if constexpr (NG == 3) {                 // LPS = 5
            if (d == 2) WAITV(10); else if (d == 1) WAITV(5); else WAITV(0);
        } else {                                 // NG == 1, LPS = 3
            if (d == 2) WAITV(6); else if (d == 1) WAITV(3); else WAITV(0);
        }
        __builtin_amdgcn_s_barrier();            // all waves' stage(j) resident
        MEMFENCE;                                // pin ds_reads below barrier
        if (j + 3 < KSTEPS) stage(j + 3, (j + 3) & 3);
        compute(j, j & 3);
    }

    const int mrow_base = m0 + wm * 64;
#pragma unroll
    for (int r = 0; r < 4; ++r) {
#pragma unroll
        for (int c = 0; c < 2; ++c) {
            int nn_ = n0 + wn * 32 + c * 16 + l16;
#pragma unroll
            for (int i = 0; i < 4; ++i) {
                int m = mrow_base + r * 16 + lhalf * 4 + i;
                if (m >= M) continue;
                if constexpr (EPI == 0) {
#pragma unroll
                    for (int g = 0; g < NG; ++g) {
                        float v = acc[g][r][c][i];
                        if (bias != nullptr && nn_ < HIDDEN) v += bias[g * HIDDEN + nn_];
                        C1[(size_t)m * ldc + g * 320 + nn_] = f2bf1(v);
                    }
                } else if constexpr (EPI == 2) {
                    if (nn_ < HIDDEN) {
                        float v = acc[0][r][c][i] + (bias ? bias[nn_] : 0.f);
                        v = fmaxf(v, 0.f);
                        if (omask) v *= omask[m];
                        outp[(size_t)m * HIDDEN + nn_] = v;
                    }
                } else { // EPI == 3: fused GRU
                    float rl = acc[0][r][c][i] + bias[nn_];
                    float zl = acc[1][r][c][i] + bias[320 + nn_];
                    float in_ = acc[2][r][c][i] + bias[640 + nn_];
                    float hn_ = acc[3][r][c][i] + bias[960 + nn_];
                    float hv = bf2f(hbuf[(size_t)m * HP + nn_]);
                    float rr = sigm(rl);
                    float zz = sigm(zl);
                    float nv = tanh_s(in_ + rr * hn_);
                    float msg = (1.f - zz) * nv + zz * hv;
                    if (m == 0) msg = 0.f;
                    C1[(size_t)m * HP + nn_] = f2bf1(msg);
                }
            }
        }
    }
}

// a_message[a, :] = sum_j message[a2b[a,j], :]
__global__ __launch_bounds__(256) void gather_sum_k(
    const u16* __restrict__ msg, const int* __restrict__ a2b, u16* __restrict__ amsg)
{
    int u = blockIdx.x * 256 + threadIdx.x;
    if (u >= N_ATOMS * 40) return;
    int a = u / 40, c = u - a * 40;
    const uint4* mp = (const uint4*)msg;
    float s[8];
#pragma unroll
    for (int t = 0; t < 8; ++t) s[t] = 0.f;
#pragma unroll
    for (int j = 0; j < MAX_NB; ++j) {
        int b = a2b[a * MAX_NB + j];
        uint4 v = mp[(size_t)b * 40 + c];
        s[0] += bf2f((u16)(v.x & 0xffff)); s[1] += bf2f((u16)(v.x >> 16));
        s[2] += bf2f((u16)(v.y & 0xffff)); s[3] += bf2f((u16)(v.y >> 16));
        s[4] += bf2f((u16)(v.z & 0xffff)); s[5] += bf2f((u16)(v.z >> 16));
        s[6] += bf2f((u16)(v.w & 0xffff)); s[7] += bf2f((u16)(v.w >> 16));
    }
    uint4 o;
    o.x = cvt_pk_bf16(s[0], s[1]);
    o.y = cvt_pk_bf16(s[2], s[3]);
    o.z = cvt_pk_bf16(s[4], s[5]);
    o.w = cvt_pk_bf16(s[6], s[7]);
    ((uint4*)amsg)[(size_t)a * 40 + c] = o;
}

// h[b, :] = amsg[b2a[b], :] - msg[b2revb[b], :]
__global__ __launch_bounds__(256) void build_h_k(
    const u16* __restrict__ amsg, const u16* __restrict__ msg,
    const int* __restrict__ b2a, const int* __restrict__ b2revb, u16* __restrict__ h)
{
    int u = blockIdx.x * 256 + threadIdx.x;
    if (u >= N_BONDS * 40) return;
    int b = u / 40, c = u - b * 40;
    uint4 va = ((const uint4*)amsg)[(size_t)b2a[b] * 40 + c];
    uint4 vm = ((const uint4*)msg)[(size_t)b2revb[b] * 40 + c];
    uint4 o;
    o.x = cvt_pk_bf16(bf2f((u16)(va.x & 0xffff)) - bf2f((u16)(vm.x & 0xffff)),
                      bf2f((u16)(va.x >> 16))    - bf2f((u16)(vm.x >> 16)));
    o.y = cvt_pk_bf16(bf2f((u16)(va.y & 0xffff)) - bf2f((u16)(vm.y & 0xffff)),
                      bf2f((u16)(va.y >> 16))    - bf2f((u16)(vm.y >> 16)));
    o.z = cvt_pk_bf16(bf2f((u16)(va.z & 0xffff)) - bf2f((u16)(vm.z & 0xffff)),
                      bf2f((u16)(va.z >> 16))    - bf2f((u16)(vm.z >> 16)));
    o.w = cvt_pk_bf16(bf2f((u16)(va.w & 0xffff)) - bf2f((u16)(vm.w & 0xffff)),
                      bf2f((u16)(va.w >> 16))    - bf2f((u16)(vm.w >> 16)));
    ((uint4*)h)[(size_t)b * 40 + c] = o;
}

// generic pad+cast fp32 -> bf16
__global__ __launch_bounds__(256) void padcast_k(
    const float* __restrict__ src, int srows, int scols,
    u16* __restrict__ dst, int drows, int dcols)
{
    int idx = blockIdx.x * 256 + threadIdx.x;
    if (idx >= drows * dcols) return;
    int r = idx / dcols, c = idx - r * dcols;
    float v = (r < srows && c < scols) ? src[(size_t)r * scols + c] : 0.f;
    dst[idx] = f2bf(v);
}

// Wf[900][160] fp32 = W_ih[900][300] @ W_i[300][147]
__global__ __launch_bounds__(256) void wf_k(
    const float* __restrict__ W_ih, const float* __restrict__ W_i, float* __restrict__ Wf)
{
    int idx = blockIdx.x * 256 + threadIdx.x;
    if (idx >= 900 * 160) return;
    int r = idx / 160, c = idx - r * 160;
    float s = 0.f;
    if (c < BOND_FDIM) {
        for (int k = 0; k < HIDDEN; ++k)
            s += W_ih[(size_t)r * HIDDEN + k] * W_i[(size_t)k * BOND_FDIM + c];
    }
    Wf[idx] = s;
}

// W4[4][320][480]
__global__ __launch_bounds__(256) void prep_W4_k(
    const float* __restrict__ Wf, const float* __restrict__ W_hh, u16* __restrict__ W4)
{
    int idx = blockIdx.x * 256 + threadIdx.x;
    if (idx >= 4 * HP * 480) return;
    int g = idx / (HP * 480); int rem = idx - g * HP * 480;
    int n = rem / 480, k = rem - n * 480;
    float v = 0.f;
    if (n < HIDDEN) {
        if (g <= 1) {
            if (k < KB_PAD) v = Wf[(size_t)(g * HIDDEN + n) * 160 + k];
            else if (k < KB_PAD + HIDDEN) v = W_hh[(size_t)(g * HIDDEN + n) * HIDDEN + (k - KB_PAD)];
        } else if (g == 2) {
            if (k < KB_PAD) v = Wf[(size_t)(2 * HIDDEN + n) * 160 + k];
        } else {
            if (k >= KB_PAD && k < KB_PAD + HIDDEN) v = W_hh[(size_t)(2 * HIDDEN + n) * HIDDEN + (k - KB_PAD)];
        }
    }
    W4[idx] = f2bf(v);
}

// bias4[4*320]
__global__ __launch_bounds__(256) void bias4_k(
    const float* __restrict__ b_ih, const float* __restrict__ b_hh, float* __restrict__ b4)
{
    int idx = blockIdx.x * 256 + threadIdx.x;
    if (idx >= 4 * HP) return;
    int g = idx / HP, n = idx - g * HP;
    float v = 0.f;
    if (n < HIDDEN) {
        if (g == 0) v = b_ih[n] + b_hh[n];
        else if (g == 1) v = b_ih[HIDDEN + n] + b_hh[HIDDEN + n];
        else if (g == 2) v = b_ih[2 * HIDDEN + n];
        else v = b_hh[2 * HIDDEN + n];
    }
    b4[idx] = v;
}

// W_o [300][433] -> [320][480]
__global__ __launch_bounds__(256) void padWo_k(const float* __restrict__ src, u16* __restrict__ dst)
{
    int idx = blockIdx.x * 256 + threadIdx.x;
    if (idx >= HP * 480) return;
    int n = idx / 480, k = idx - n * 480;
    float v = 0.f;
    if (n < HIDDEN) {
        if (k < ATOM_FDIM) v = src[(size_t)n * 433 + k];
        else if (k >= KA_PAD && k < KA_PAD + HIDDEN) v = src[(size_t)n * 433 + ATOM_FDIM + (k - KA_PAD)];
    }
    dst[idx] = f2bf(v);
}

__global__ __launch_bounds__(256) void sentinel_k(float* __restrict__ out, int n)
{
    int i = blockIdx.x * 256 + threadIdx.x;
    if (i < n) out[i] = 31415.0f;
}

extern "C" void kernel_launch(void* const* d_in, const int* in_sizes, int n_in,
                              void* d_out, int out_size, void* d_ws, size_t ws_size,
                              hipStream_t stream)
{
    const float* f_atoms = (const float*)d_in[0];
    const float* f_bonds = (const float*)d_in[1];
    const int*   a2b     = (const int*)d_in[2];
    const int*   b2a     = (const int*)d_in[3];
    const int*   b2revb  = (const int*)d_in[4];
    const float* maskp   = (const float*)d_in[8];
    const float* W_i     = (const float*)d_in[9];
    const float* W_ih    = (const float*)d_in[10];
    const float* W_hh    = (const float*)d_in[11];
    const float* b_ih    = (const float*)d_in[12];
    const float* b_hh    = (const float*)d_in[13];
    const float* W_o_w   = (const float*)d_in[14];
    const float* W_o_b   = (const float*)d_in[15];
    float* out = (float*)d_out;

    char* ws = (char*)d_ws;
    size_t off = 0;
    auto alloc = [&](size_t bytes) -> char* {
        char* p = ws + off;
        off += (bytes + 255) & ~(size_t)255;
        return p;
    };
    u16*   Wi_p   = (u16*)alloc((size_t)HP * KB_PAD * 2);
    u16*   W4     = (u16*)alloc((size_t)4 * HP * 480 * 2);
    u16*   Wo_p   = (u16*)alloc((size_t)HP * 480 * 2);
    float* bias4  = (float*)alloc((size_t)4 * HP * 4);
    float* Wf     = (float*)alloc((size_t)900 * 160 * 4);
    u16*   fa_p   = (u16*)alloc((size_t)NA_PAD * KA_PAD * 2);
    u16*   fb_p   = (u16*)alloc((size_t)NB_PAD * KB_PAD * 2);
    u16*   message= (u16*)alloc((size_t)NB_PAD * HP * 2);
    u16*   hbuf   = (u16*)alloc((size_t)NB_PAD * HP * 2);
    u16*   amsg   = (u16*)alloc((size_t)NA_PAD * HP * 2);

    if (off > ws_size) {
        sentinel_k<<<(out_size + 255) / 256, 256, 0, stream>>>(out, out_size);
        return;
    }

    // --- weight / feature prep ---
    padcast_k<<<(HP * KB_PAD + 255) / 256, 256, 0, stream>>>(W_i, HIDDEN, BOND_FDIM, Wi_p, HP, KB_PAD);
    padcast_k<<<(NB_PAD * KB_PAD + 255) / 256, 256, 0, stream>>>(f_bonds, N_BONDS, BOND_FDIM, fb_p, NB_PAD, KB_PAD);
    padcast_k<<<(NA_PAD * KA_PAD + 255) / 256, 256, 0, stream>>>(f_atoms, N_ATOMS, ATOM_FDIM, fa_p, NA_PAD, KA_PAD);
    wf_k<<<(900 * 160 + 255) / 256, 256, 0, stream>>>(W_ih, W_i, Wf);
    prep_W4_k<<<(4 * HP * 480 + 255) / 256, 256, 0, stream>>>(Wf, W_hh, W4);
    bias4_k<<<(4 * HP + 255) / 256, 256, 0, stream>>>(b_ih, b_hh, bias4);
    padWo_k<<<(HP * 480 + 255) / 256, 256, 0, stream>>>(W_o_w, Wo_p);

    dim3 blk(256);
    dim3 gB(NB_PAD / 128, 5);
    // message = inp = f_bonds @ W_i.T   (K=160 -> 5 ksteps, A only)
    gemm_k<1, 0, 0, 5, 5><<<gB, blk, 0, stream>>>(
        fb_p, KB_PAD * 2, fb_p, KB_PAD * 2, Wi_p, KB_PAD * 2,
        N_BONDS, message, HP, nullptr, nullptr, nullptr, nullptr);

    dim3 gBf(NB_PAD / 128 * 5);      // 3520, %8==0 -> bijective XCD swizzle
    for (int d = 0; d < DEPTH - 1; ++d) {
        gather_sum_k<<<(N_ATOMS * 40 + 255) / 256, 256, 0, stream>>>(message, a2b, amsg);
        build_h_k<<<(N_BONDS * 40 + 255) / 256, 256, 0, stream>>>(amsg, message, b2a, b2revb, hbuf);
        // fused GRU: A = [f_bonds_pad | h], 3 B-slots, 4 acc gates, K = 480
        gemm_k<3, 3, 1, 15, 5><<<gBf, blk, 0, stream>>>(
            fb_p, KB_PAD * 2, hbuf, HP * 2, W4, 480 * 2,
            N_BONDS, message, HP, bias4, hbuf, nullptr, nullptr);
    }
    gather_sum_k<<<(N_ATOMS * 40 + 255) / 256, 256, 0, stream>>>(message, a2b, amsg);
    dim3 gO(NA_PAD / 128, 5);
    gemm_k<1, 2, 0, 15, 5><<<gO, blk, 0, stream>>>(
        fa_p, KA_PAD * 2, amsg, HP * 2, Wo_p, 480 * 2,
        N_ATOMS, nullptr, 0, W_o_b, nullptr, out, maskp);
}

// Round 11
// 1309.828 us; speedup vs baseline: 1.2783x; 1.0311x over previous
//
#include <hip/hip_runtime.h>
#include <hip/hip_bf16.h>
#include <stdint.h>

#define N_ATOMS 40000
#define N_BONDS 90000
#define MAX_NB 6
#define ATOM_FDIM 133
#define BOND_FDIM 147
#define HIDDEN 300
#define DEPTH 6

// padded dims
#define KA2 192         // A-side K pad (bond 147 / atom 133 -> 192 = 1.5 ksteps of 64 elems)
#define HP 320
#define KW 512          // W4 / Wo K pad: 192 (A-part) + 320 (hidden) = 512 = 4 ksteps
#define NB_PAD 90112    // mult of 128 (704 tiles)
#define NA_PAD 40064

typedef unsigned short u16;
typedef unsigned int uint32;

typedef __bf16 bf16x8 __attribute__((ext_vector_type(8)));
typedef float f32x4 __attribute__((ext_vector_type(4)));

#define GLOBAL_AS __attribute__((address_space(1)))
#define LDS_AS __attribute__((address_space(3)))

__device__ __forceinline__ void async_copy16(const void* g, void* l) {
    __builtin_amdgcn_global_load_lds((GLOBAL_AS void*)(void*)g,
                                     (LDS_AS void*)l, 16, 0, 0);
}

__device__ __forceinline__ float bf2f(u16 s) {
    union { uint32 u; float f; } v; v.u = ((uint32)s) << 16; return v.f;
}
__device__ __forceinline__ u16 f2bf(float f) {
    union { float f; uint32 u; } v; v.f = f;
    uint32 r = v.u + 0x7fffu + ((v.u >> 16) & 1u);
    return (u16)(r >> 16);
}
__device__ __forceinline__ uint32 cvt_pk_bf16(float lo, float hi) {
    uint32 r;
    asm("v_cvt_pk_bf16_f32 %0, %1, %2" : "=v"(r) : "v"(lo), "v"(hi));
    return r;
}
__device__ __forceinline__ u16 f2bf1(float f) {
    return (u16)(cvt_pk_bf16(f, f) & 0xffffu);
}
__device__ __forceinline__ float sigm(float x) { return 1.f / (1.f + __expf(-x)); }
__device__ __forceinline__ float tanh_s(float x) {
    float e = __expf(-2.f * fabsf(x));
    float t = (1.f - e) / (1.f + e);
    return x >= 0.f ? t : -t;
}

// ---------------------------------------------------------------------------
// GEMM, R11: per-kstep K-chunk doubled 64B -> 128B (BK=64 elems).
// R8 ablation showed cost is ~FIXED PER K-STEP ROUND (serial == 2-buf == 4-buf
// counted == 1.5x occupancy, all ~170-176us): per-round toll, not per-byte.
// So: halve the rounds. GRU K: 480->512 elems (A-part padded 160->192 so the
// A/A2 switch lands on a step boundary: KSPLIT=3 of KSTEPS=8). Initial: 3
// steps; final: 8. Per round per wave: 4 A-glds + NG*2 B-glds, 2x(4 A + NG*2 B)
// ds_read_b128, NG*16 MFMA.
// Structure: 2-buf __syncthreads double buffer (R8-V3, measured <= 4-buf).
// LDS/block = 2 x (16 + NG*8) KB = 80 KB at NG=3 -> still 2 blocks/CU
// (register-bound anyway; no occupancy change, avoiding m132's cliff).
// Swizzle (both-sides, generalized to 8 slots/row): source 16B-slot
// sw = slot*16 ^ ((row&7)<<4), glds dest linear, ds_read XORs the same term
// (lane-const: row&7 == l16&7). 8 distinct slots per 8-lane group -> 2-way
// bank aliasing = free.
// Gate sparsity (EPI3): slot2 rows = i_n (ks<KSPLIT) / h_n (ks>=KSPLIT); h_n's
// W_hh block occupies k-bytes [384,1024) of the gate-3 row = exactly steps 3-7.
// EPI 0: store bf16. EPI 2: bias+relu+mask fp32 out. EPI 3: fused GRU.
// ---------------------------------------------------------------------------
template<int NG, int EPI, int SWZ, int KSTEPS, int KSPLIT>
__global__ __launch_bounds__(256, 2) void gemm_k(
    const u16* __restrict__ A, int ldaB,
    const u16* __restrict__ A2, int lda2B,
    const u16* __restrict__ Bw, int ldbB,
    int M,
    u16* __restrict__ C1, int ldc,
    const float* __restrict__ bias,
    const u16* __restrict__ hbuf,
    float* __restrict__ outp, const float* __restrict__ omask)
{
    constexpr int NACC = (EPI == 3) ? 4 : NG;
    constexpr int CB = NG * 2;                   // B glds-chunks per wave
    __shared__ __align__(16) u16 lsA[2][128 * 64];
    __shared__ __align__(16) u16 lsB[2][NG * 64 * 64];

    const int tid = threadIdx.x;
    const int wv = tid >> 6, ln = tid & 63;
    const int wm = wv >> 1, wn = wv & 1;        // 2M x 2N wave grid
    int bxi, byi;
    if constexpr (SWZ) {
        int bid = blockIdx.x;
        int chunk = bid & 7, pos = bid >> 3;
        int orig = chunk * (int)(gridDim.x >> 3) + pos;
        bxi = orig / 5; byi = orig - bxi * 5;
    } else {
        bxi = blockIdx.x; byi = blockIdx.y;
    }
    const int m0 = bxi * 128;
    const int n0 = byi * 64;
    const int lhalf = ln >> 4, l16 = ln & 15;

    f32x4 acc[NACC][4][2];
#pragma unroll
    for (int g = 0; g < NACC; ++g)
#pragma unroll
        for (int r = 0; r < 4; ++r)
#pragma unroll
            for (int c = 0; c < 2; ++c) { f32x4 z = {0.f, 0.f, 0.f, 0.f}; acc[g][r][c] = z; }

    // ---- A staging (16 chunks of 64 lanes x 16B; 4 per wave), source-swizzled ----
    const char* pAlo[4];
    const char* pAhi[4];
    int dstA[4];
#pragma unroll
    for (int c = 0; c < 4; ++c) {
        int g = (wv * 4 + c) * 64 + ln;          // 16B-unit index in 128x8 grid
        int row = g >> 3, slot = g & 7;
        int sw = (slot * 16) ^ ((row & 7) << 4);
        pAlo[c] = (const char*)A  + (size_t)(m0 + row) * ldaB  + sw;
        pAhi[c] = (const char*)A2 + (size_t)(m0 + row) * lda2B + sw;
        dstA[c] = g * 8;                          // u16 index (linear dest)
    }
    // ---- B staging (NG*8 chunks; CB per wave), source-swizzled ----
    const char* pBlo[CB];
    const char* pBhi[CB];
    int dstB[CB];
#pragma unroll
    for (int c = 0; c < CB; ++c) {
        int q = wv * CB + c;                      // chunk id in [0, NG*8)
        int gate = q >> 3, sub = q & 7;
        int unit = sub * 64 + ln;                 // 16B-unit within gate tile (64x8)
        int row = unit >> 3, slot = unit & 7;
        int sw = (slot * 16) ^ ((row & 7) << 4);
        int ghi = (EPI == 3 && gate == 2) ? 3 : gate;
        pBlo[c] = (const char*)Bw + (size_t)(gate * 320 + n0 + row) * ldbB + sw;
        pBhi[c] = (const char*)Bw + (size_t)(ghi  * 320 + n0 + row) * ldbB + sw;
        dstB[c] = gate * 4096 + unit * 8;         // u16 index (linear dest)
    }

    auto stage = [&](int ks, int buf) {
#pragma unroll
        for (int c = 0; c < 4; ++c) {
            const char* src = (ks < KSPLIT) ? (pAlo[c] + ks * 128)
                                            : (pAhi[c] + (ks - KSPLIT) * 128);
            async_copy16(src, &lsA[buf][dstA[c]]);
        }
#pragma unroll
        for (int c = 0; c < CB; ++c) {
            const char* src = ((ks < KSPLIT) ? pBlo[c] : pBhi[c]) + ks * 128;
            async_copy16(src, &lsB[buf][dstB[c]]);
        }
    };

    // read-side swizzle term (u16 units); row&7 == l16&7 for all frag rows
    const int rsw = (l16 & 7) << 3;
    int arow[4];
#pragma unroll
    for (int r = 0; r < 4; ++r) arow[r] = (wm * 64 + r * 16 + l16) * 64;
    int brow[2];
#pragma unroll
    for (int c = 0; c < 2; ++c) brow[c] = (wn * 32 + c * 16 + l16) * 64;

    auto compute = [&](int j, int buf) {
#pragma unroll
        for (int u = 0; u < 2; ++u) {             // two K=32 sub-steps per round
            const int koff = (u * 32 + lhalf * 8) ^ rsw;
            bf16x8 af[4];
#pragma unroll
            for (int r = 0; r < 4; ++r)
                af[r] = *(const bf16x8*)&lsA[buf][arow[r] + koff];
#pragma unroll
            for (int g = 0; g < NG; ++g) {
#pragma unroll
                for (int c = 0; c < 2; ++c) {
                    bf16x8 bf = *(const bf16x8*)&lsB[buf][g * 4096 + brow[c] + koff];
#pragma unroll
                    for (int r = 0; r < 4; ++r) {
                        if constexpr (EPI == 3) {
                            if (g == 2) {
                                if (j < KSPLIT)
                                    acc[2][r][c] = __builtin_amdgcn_mfma_f32_16x16x32_bf16(af[r], bf, acc[2][r][c], 0, 0, 0);
                                else
                                    acc[3][r][c] = __builtin_amdgcn_mfma_f32_16x16x32_bf16(af[r], bf, acc[3][r][c], 0, 0, 0);
                            } else {
                                acc[g][r][c] = __builtin_amdgcn_mfma_f32_16x16x32_bf16(af[r], bf, acc[g][r][c], 0, 0, 0);
                            }
                        } else {
                            acc[g][r][c] = __builtin_amdgcn_mfma_f32_16x16x32_bf16(af[r], bf, acc[g][r][c], 0, 0, 0);
                        }
                    }
                }
            }
        }
    };

    stage(0, 0);
    __syncthreads();
#pragma unroll
    for (int j = 0; j < KSTEPS; ++j) {
        if (j + 1 < KSTEPS) stage(j + 1, (j + 1) & 1);
        compute(j, j & 1);
        __syncthreads();
    }

    const int mrow_base = m0 + wm * 64;
#pragma unroll
    for (int r = 0; r < 4; ++r) {
#pragma unroll
        for (int c = 0; c < 2; ++c) {
            int nn_ = n0 + wn * 32 + c * 16 + l16;
#pragma unroll
            for (int i = 0; i < 4; ++i) {
                int m = mrow_base + r * 16 + lhalf * 4 + i;
                if (m >= M) continue;
                if constexpr (EPI == 0) {
#pragma unroll
                    for (int g = 0; g < NG; ++g) {
                        float v = acc[g][r][c][i];
                        if (bias != nullptr && nn_ < HIDDEN) v += bias[g * HIDDEN + nn_];
                        C1[(size_t)m * ldc + g * 320 + nn_] = f2bf1(v);
                    }
                } else if constexpr (EPI == 2) {
                    if (nn_ < HIDDEN) {
                        float v = acc[0][r][c][i] + (bias ? bias[nn_] : 0.f);
                        v = fmaxf(v, 0.f);
                        if (omask) v *= omask[m];
                        outp[(size_t)m * HIDDEN + nn_] = v;
                    }
                } else { // EPI == 3: fused GRU
                    float rl = acc[0][r][c][i] + bias[nn_];
                    float zl = acc[1][r][c][i] + bias[320 + nn_];
                    float in_ = acc[2][r][c][i] + bias[640 + nn_];
                    float hn_ = acc[3][r][c][i] + bias[960 + nn_];
                    float hv = bf2f(hbuf[(size_t)m * HP + nn_]);
                    float rr = sigm(rl);
                    float zz = sigm(zl);
                    float nv = tanh_s(in_ + rr * hn_);
                    float msg = (1.f - zz) * nv + zz * hv;
                    if (m == 0) msg = 0.f;
                    C1[(size_t)m * HP + nn_] = f2bf1(msg);
                }
            }
        }
    }
}

// a_message[a, :] = sum_j message[a2b[a,j], :]
__global__ __launch_bounds__(256) void gather_sum_k(
    const u16* __restrict__ msg, const int* __restrict__ a2b, u16* __restrict__ amsg)
{
    int u = blockIdx.x * 256 + threadIdx.x;
    if (u >= N_ATOMS * 40) return;
    int a = u / 40, c = u - a * 40;
    const uint4* mp = (const uint4*)msg;
    float s[8];
#pragma unroll
    for (int t = 0; t < 8; ++t) s[t] = 0.f;
#pragma unroll
    for (int j = 0; j < MAX_NB; ++j) {
        int b = a2b[a * MAX_NB + j];
        uint4 v = mp[(size_t)b * 40 + c];
        s[0] += bf2f((u16)(v.x & 0xffff)); s[1] += bf2f((u16)(v.x >> 16));
        s[2] += bf2f((u16)(v.y & 0xffff)); s[3] += bf2f((u16)(v.y >> 16));
        s[4] += bf2f((u16)(v.z & 0xffff)); s[5] += bf2f((u16)(v.z >> 16));
        s[6] += bf2f((u16)(v.w & 0xffff)); s[7] += bf2f((u16)(v.w >> 16));
    }
    uint4 o;
    o.x = cvt_pk_bf16(s[0], s[1]);
    o.y = cvt_pk_bf16(s[2], s[3]);
    o.z = cvt_pk_bf16(s[4], s[5]);
    o.w = cvt_pk_bf16(s[6], s[7]);
    ((uint4*)amsg)[(size_t)a * 40 + c] = o;
}

// h[b, :] = amsg[b2a[b], :] - msg[b2revb[b], :]
__global__ __launch_bounds__(256) void build_h_k(
    const u16* __restrict__ amsg, const u16* __restrict__ msg,
    const int* __restrict__ b2a, const int* __restrict__ b2revb, u16* __restrict__ h)
{
    int u = blockIdx.x * 256 + threadIdx.x;
    if (u >= N_BONDS * 40) return;
    int b = u / 40, c = u - b * 40;
    uint4 va = ((const uint4*)amsg)[(size_t)b2a[b] * 40 + c];
    uint4 vm = ((const uint4*)msg)[(size_t)b2revb[b] * 40 + c];
    uint4 o;
    o.x = cvt_pk_bf16(bf2f((u16)(va.x & 0xffff)) - bf2f((u16)(vm.x & 0xffff)),
                      bf2f((u16)(va.x >> 16))    - bf2f((u16)(vm.x >> 16)));
    o.y = cvt_pk_bf16(bf2f((u16)(va.y & 0xffff)) - bf2f((u16)(vm.y & 0xffff)),
                      bf2f((u16)(va.y >> 16))    - bf2f((u16)(vm.y >> 16)));
    o.z = cvt_pk_bf16(bf2f((u16)(va.z & 0xffff)) - bf2f((u16)(vm.z & 0xffff)),
                      bf2f((u16)(va.z >> 16))    - bf2f((u16)(vm.z >> 16)));
    o.w = cvt_pk_bf16(bf2f((u16)(va.w & 0xffff)) - bf2f((u16)(vm.w & 0xffff)),
                      bf2f((u16)(va.w >> 16))    - bf2f((u16)(vm.w >> 16)));
    ((uint4*)h)[(size_t)b * 40 + c] = o;
}

// generic pad+cast fp32 -> bf16
__global__ __launch_bounds__(256) void padcast_k(
    const float* __restrict__ src, int srows, int scols,
    u16* __restrict__ dst, int drows, int dcols)
{
    int idx = blockIdx.x * 256 + threadIdx.x;
    if (idx >= drows * dcols) return;
    int r = idx / dcols, c = idx - r * dcols;
    float v = (r < srows && c < scols) ? src[(size_t)r * scols + c] : 0.f;
    dst[idx] = f2bf(v);
}

// Wf[900][160] fp32 = W_ih[900][300] @ W_i[300][147]  (cols >=147 zero)
__global__ __launch_bounds__(256) void wf_k(
    const float* __restrict__ W_ih, const float* __restrict__ W_i, float* __restrict__ Wf)
{
    int idx = blockIdx.x * 256 + threadIdx.x;
    if (idx >= 900 * 160) return;
    int r = idx / 160, c = idx - r * 160;
    float s = 0.f;
    if (c < BOND_FDIM) {
        for (int k = 0; k < HIDDEN; ++k)
            s += W_ih[(size_t)r * HIDDEN + k] * W_i[(size_t)k * BOND_FDIM + c];
    }
    Wf[idx] = s;
}

// W4[4][320][512]: gates r/z: [Wf(192-pad) | W_hh(300) | 0]; i_n: [Wf | 0]; h_n: [0(192) | W_hh | 0]
__global__ __launch_bounds__(256) void prep_W4_k(
    const float* __restrict__ Wf, const float* __restrict__ W_hh, u16* __restrict__ W4)
{
    int idx = blockIdx.x * 256 + threadIdx.x;
    if (idx >= 4 * HP * KW) return;
    int g = idx / (HP * KW); int rem = idx - g * HP * KW;
    int n = rem / KW, k = rem - n * KW;
    float v = 0.f;
    if (n < HIDDEN) {
        if (g <= 1) {
            if (k < 160) v = Wf[(size_t)(g * HIDDEN + n) * 160 + k];
            else if (k >= KA2 && k < KA2 + HIDDEN) v = W_hh[(size_t)(g * HIDDEN + n) * HIDDEN + (k - KA2)];
        } else if (g == 2) {
            if (k < 160) v = Wf[(size_t)(2 * HIDDEN + n) * 160 + k];
        } else { // g == 3
            if (k >= KA2 && k < KA2 + HIDDEN) v = W_hh[(size_t)(2 * HIDDEN + n) * HIDDEN + (k - KA2)];
        }
    }
    W4[idx] = f2bf(v);
}

// bias4[4*320]
__global__ __launch_bounds__(256) void bias4_k(
    const float* __restrict__ b_ih, const float* __restrict__ b_hh, float* __restrict__ b4)
{
    int idx = blockIdx.x * 256 + threadIdx.x;
    if (idx >= 4 * HP) return;
    int g = idx / HP, n = idx - g * HP;
    float v = 0.f;
    if (n < HIDDEN) {
        if (g == 0) v = b_ih[n] + b_hh[n];
        else if (g == 1) v = b_ih[HIDDEN + n] + b_hh[HIDDEN + n];
        else if (g == 2) v = b_ih[2 * HIDDEN + n];
        else v = b_hh[2 * HIDDEN + n];
    }
    b4[idx] = v;
}

// W_o [300][433] -> [320][512]: k<133 atom part, k in [192,492) hidden part
__global__ __launch_bounds__(256) void padWo_k(const float* __restrict__ src, u16* __restrict__ dst)
{
    int idx = blockIdx.x * 256 + threadIdx.x;
    if (idx >= HP * KW) return;
    int n = idx / KW, k = idx - n * KW;
    float v = 0.f;
    if (n < HIDDEN) {
        if (k < ATOM_FDIM) v = src[(size_t)n * 433 + k];
        else if (k >= KA2 && k < KA2 + HIDDEN) v = src[(size_t)n * 433 + ATOM_FDIM + (k - KA2)];
    }
    dst[idx] = f2bf(v);
}

__global__ __launch_bounds__(256) void sentinel_k(float* __restrict__ out, int n)
{
    int i = blockIdx.x * 256 + threadIdx.x;
    if (i < n) out[i] = 31415.0f;
}

extern "C" void kernel_launch(void* const* d_in, const int* in_sizes, int n_in,
                              void* d_out, int out_size, void* d_ws, size_t ws_size,
                              hipStream_t stream)
{
    const float* f_atoms = (const float*)d_in[0];
    const float* f_bonds = (const float*)d_in[1];
    const int*   a2b     = (const int*)d_in[2];
    const int*   b2a     = (const int*)d_in[3];
    const int*   b2revb  = (const int*)d_in[4];
    const float* maskp   = (const float*)d_in[8];
    const float* W_i     = (const float*)d_in[9];
    const float* W_ih    = (const float*)d_in[10];
    const float* W_hh    = (const float*)d_in[11];
    const float* b_ih    = (const float*)d_in[12];
    const float* b_hh    = (const float*)d_in[13];
    const float* W_o_w   = (const float*)d_in[14];
    const float* W_o_b   = (const float*)d_in[15];
    float* out = (float*)d_out;

    char* ws = (char*)d_ws;
    size_t off = 0;
    auto alloc = [&](size_t bytes) -> char* {
        char* p = ws + off;
        off += (bytes + 255) & ~(size_t)255;
        return p;
    };
    u16*   Wi_p   = (u16*)alloc((size_t)HP * KA2 * 2);           // [320][192]
    u16*   W4     = (u16*)alloc((size_t)4 * HP * KW * 2);        // [4][320][512]
    u16*   Wo_p   = (u16*)alloc((size_t)HP * KW * 2);            // [320][512]
    float* bias4  = (float*)alloc((size_t)4 * HP * 4);
    float* Wf     = (float*)alloc((size_t)900 * 160 * 4);
    u16*   fa_p   = (u16*)alloc((size_t)NA_PAD * KA2 * 2);       // [40064][192]
    u16*   fb_p   = (u16*)alloc((size_t)NB_PAD * KA2 * 2);       // [90112][192]
    u16*   message= (u16*)alloc((size_t)NB_PAD * HP * 2);
    u16*   hbuf   = (u16*)alloc((size_t)NB_PAD * HP * 2);
    u16*   amsg   = (u16*)alloc((size_t)NA_PAD * HP * 2);

    if (off > ws_size) {
        sentinel_k<<<(out_size + 255) / 256, 256, 0, stream>>>(out, out_size);
        return;
    }

    // --- weight / feature prep ---
    padcast_k<<<(HP * KA2 + 255) / 256, 256, 0, stream>>>(W_i, HIDDEN, BOND_FDIM, Wi_p, HP, KA2);
    padcast_k<<<((int)((size_t)NB_PAD * KA2 + 255) / 256), 256, 0, stream>>>(f_bonds, N_BONDS, BOND_FDIM, fb_p, NB_PAD, KA2);
    padcast_k<<<((int)((size_t)NA_PAD * KA2 + 255) / 256), 256, 0, stream>>>(f_atoms, N_ATOMS, ATOM_FDIM, fa_p, NA_PAD, KA2);
    wf_k<<<(900 * 160 + 255) / 256, 256, 0, stream>>>(W_ih, W_i, Wf);
    prep_W4_k<<<(4 * HP * KW + 255) / 256, 256, 0, stream>>>(Wf, W_hh, W4);
    bias4_k<<<(4 * HP + 255) / 256, 256, 0, stream>>>(b_ih, b_hh, bias4);
    padWo_k<<<(HP * KW + 255) / 256, 256, 0, stream>>>(W_o_w, Wo_p);

    dim3 blk(256);
    dim3 gB(NB_PAD / 128, 5);
    // message = inp = f_bonds @ W_i.T   (K=192 elems -> 3 ksteps of 128B, A only)
    gemm_k<1, 0, 0, 3, 3><<<gB, blk, 0, stream>>>(
        fb_p, KA2 * 2, fb_p, KA2 * 2, Wi_p, KA2 * 2,
        N_BONDS, message, HP, nullptr, nullptr, nullptr, nullptr);

    dim3 gBf(NB_PAD / 128 * 5);      // 3520, %8==0 -> bijective XCD swizzle
    for (int d = 0; d < DEPTH - 1; ++d) {
        gather_sum_k<<<(N_ATOMS * 40 + 255) / 256, 256, 0, stream>>>(message, a2b, amsg);
        build_h_k<<<(N_BONDS * 40 + 255) / 256, 256, 0, stream>>>(amsg, message, b2a, b2revb, hbuf);
        // fused GRU: A = [fb_p(192) | hbuf(320)], K = 512 elems = 8 ksteps, split 3
        gemm_k<3, 3, 1, 8, 3><<<gBf, blk, 0, stream>>>(
            fb_p, KA2 * 2, hbuf, HP * 2, W4, KW * 2,
            N_BONDS, message, HP, bias4, hbuf, nullptr, nullptr);
    }
    gather_sum_k<<<(N_ATOMS * 40 + 255) / 256, 256, 0, stream>>>(message, a2b, amsg);
    dim3 gO(NA_PAD / 128, 5);
    gemm_k<1, 2, 0, 8, 3><<<gO, blk, 0, stream>>>(
        fa_p, KA2 * 2, amsg, HP * 2, Wo_p, KW * 2,
        N_ATOMS, nullptr, 0, W_o_b, nullptr, out, maskp);
}